// Round 2
// baseline (201.712 us; speedup 1.0000x reference)
//
#include <hip/hip_runtime.h>

#define Bb 4
#define Tt 64
#define Nn 16
#define Mm 8
#define Dd 512
#define RR 32      // Bb*Mm rows per (t,n) group
#define QSTR 536   // padded LDS row stride in u16: holds 528 (x,1,pad) cols;
                   // 536*2=1072 B = 268 dw == 12 mod 32 -> b128 reads conflict-free
#define VOFF 270336  // u16 offset of Wv region in workspace (16*33*512)

typedef __attribute__((ext_vector_type(8))) short bf16x8;
typedef __attribute__((ext_vector_type(16))) float f32x16;

__device__ __forceinline__ unsigned short f2bf(float f) {
    union { float f; unsigned int u; } v; v.f = f;
    unsigned int r = (v.u + 0x7fffu + ((v.u >> 16) & 1u)) >> 16;  // RNE
    return (unsigned short)r;
}
__device__ __forceinline__ float bf2f(unsigned short h) {
    union { unsigned int u; float f; } v; v.u = ((unsigned int)h) << 16;
    return v.f;
}

// ---- Pack Wv into bf16 32x32 MFMA B-fragment order at VOFF ----
// word = VOFF + ((e*32+kk)*64 + hi*32 + n)*8 + j  <-  Wv[e*32+n][kk*16+hi*8+j]
__global__ __launch_bounds__(256) void pack_wv_kernel(
    const float* __restrict__ Wv, unsigned short* __restrict__ Wb)
{
    int idx = blockIdx.x * 256 + threadIdx.x;   // 65536 ushort4
    int o = idx << 2;
    int j  = o & 7;
    int n  = (o >> 3) & 31;
    int hi = (o >> 8) & 1;
    int ekk = o >> 9;            // e*32+kk
    int kk = ekk & 31;
    int e  = ekk >> 5;           // 0..15
    int row = e * 32 + n;
    int d = kk * 16 + hi * 8 + j;
    float4 v = *(const float4*)(Wv + row * Dd + d);
    ushort4 o4;
    o4.x = f2bf(v.x); o4.y = f2bf(v.y); o4.z = f2bf(v.z); o4.w = f2bf(v.w);
    *(ushort4*)(Wb + VOFF + o) = o4;
}

// ---- Compute Atilde = Wq^T @ Wk (+ ck = Wk^T bq as K-slot 32) and pack ----
// B-frag order, 16 tiles x 33 kk: word[((eT*33+kk)*512) + (h*32+col)*8 + j]
//   = Atilde[d][eT*32+col] for d=kk*16+h*8+j < 512;  kk=32,h=0,j=0 slot = ck.
// Block (eT, dT) computes the 32x32 tile T[d'][e'] = sum_n Wq[n][dT*32+d']*Wk[n][eT*32+e'].
__global__ __launch_bounds__(256) void pack_bqk_kernel(
    const float* __restrict__ Wq, const float* __restrict__ Wk,
    const float* __restrict__ bq, unsigned short* __restrict__ Wb)
{
    __shared__ unsigned short lq[512 * 32];
    __shared__ unsigned short lk[512 * 32];
    const int tid = threadIdx.x;
    const int eT = blockIdx.x & 15;
    const int dT = blockIdx.x >> 4;

    #pragma unroll
    for (int i = 0; i < 16; ++i) {
        int fi = i * 256 + tid;          // 4096 float4 per matrix
        int n = fi >> 3;
        int c4 = (fi & 7) << 2;
        float4 vq = *(const float4*)(Wq + n * Dd + dT * 32 + c4);
        float4 vk = *(const float4*)(Wk + n * Dd + eT * 32 + c4);
        ushort4 a, b;
        a.x = f2bf(vq.x); a.y = f2bf(vq.y); a.z = f2bf(vq.z); a.w = f2bf(vq.w);
        b.x = f2bf(vk.x); b.y = f2bf(vk.y); b.z = f2bf(vk.z); b.w = f2bf(vk.w);
        *(ushort4*)(&lq[n * 32 + c4]) = a;
        *(ushort4*)(&lk[n * 32 + c4]) = b;
    }
    __syncthreads();

    {
        int dp = tid & 31;              // d'
        int e0 = (tid >> 5) << 2;       // e' base (4 outputs)
        float acc0 = 0.f, acc1 = 0.f, acc2 = 0.f, acc3 = 0.f;
        for (int n = 0; n < 512; ++n) {
            float a = bf2f(lq[n * 32 + dp]);
            acc0 += a * bf2f(lk[n * 32 + e0 + 0]);
            acc1 += a * bf2f(lk[n * 32 + e0 + 1]);
            acc2 += a * bf2f(lk[n * 32 + e0 + 2]);
            acc3 += a * bf2f(lk[n * 32 + e0 + 3]);
        }
        int kk = dT * 2 + (dp >> 4);
        int k16 = dp & 15;
        int h = k16 >> 3, j = k16 & 7;
        long base = ((long)(eT * 33 + kk) << 9) + ((h * 32) << 3) + j;
        Wb[base + ((e0 + 0) << 3)] = f2bf(acc0);
        Wb[base + ((e0 + 1) << 3)] = f2bf(acc1);
        Wb[base + ((e0 + 2) << 3)] = f2bf(acc2);
        Wb[base + ((e0 + 3) << 3)] = f2bf(acc3);
    }

    if (dT == 0) {
        // zero the kk=32 (bias) fragment, then write ck into h=0,j=0 slots
        long b32 = (long)(eT * 33 + 32) << 9;
        if (tid < 256) { Wb[b32 + tid] = 0; Wb[b32 + 256 + tid] = 0; }
        __syncthreads();
        if (tid < 32) {
            float c = 0.f;
            for (int n = 0; n < 512; ++n) c += bf2f(lk[n * 32 + tid]) * bq[n];
            Wb[b32 + (tid << 3)] = f2bf(c);   // col=tid, h=0, j=0
        }
    }
}

// One block per TWO (t,n) groups. 1024 threads = 16 waves.
// Phase 2: Y = x~ @ [Atilde; ck]  (one GEMM replaces Q and K; biases folded/dropped
//   since softmax is invariant to per-row(m) constants).
// Phase 3: S[m,k] = sum_b sum_e Y[bm,e] x[bk,e] via in-register fold-reduce.
// V eliminated algebraically: out = (P@x)@Wv^T + bv.
__global__ __launch_bounds__(1024, 4) void fused_attn_kernel(
    const float* __restrict__ x, const unsigned short* __restrict__ Wb,
    const float* __restrict__ bv, float* __restrict__ out)
{
    __shared__ unsigned short lds_x[2][RR * QSTR];  // 68,608 B (x~, later y, bf16)
    __shared__ float lds_s[2][64];                  // scores -> probs

    const int tid = threadIdx.x;
    const int lane = tid & 63;
    const int wave = tid >> 6;       // 0..15
    const int arow = lane & 31;
    const int ahalf = lane >> 5;
    const int l5 = lane & 31;

    const int gi0 = blockIdx.x << 1;
    const int t = gi0 >> 4;
    const int n0 = gi0 & 15;
    const int rot = (blockIdx.x * 7) & 31;   // decorrelate L2 address streams

    // B~ fragment base for this wave's e-tile (33 kk-fragments of 512 u16)
    const unsigned short* wb = Wb + (long)wave * (33 * 512) + (lane << 3);
    // kk order: rotate the 32 data steps per block; bias step (32) always last
    #define KOF(s) ((s) + rot >= 32 ? (s) + rot - 32 : (s) + rot)

    bf16x8 pf[4];
    pf[0] = *(const bf16x8*)(wb + KOF(0) * 512);
    pf[1] = *(const bf16x8*)(wb + KOF(1) * 512);
    pf[2] = *(const bf16x8*)(wb + KOF(2) * 512);
    pf[3] = *(const bf16x8*)(wb + KOF(3) * 512);

    if (tid < 128) lds_s[tid >> 6][tid & 63] = 0.f;

    // ---- Phase 1: stage x~ (bf16) ----
    #pragma unroll
    for (int i = 0; i < 8; ++i) {
        int fi = i * 1024 + tid;     // 8192 float4
        int g = fi >> 12;
        int rem = fi & 4095;
        int row = rem >> 7;
        int d = (rem & 127) << 2;
        int b = row >> 3, m = row & 7;
        float4 v = *(const float4*)(x + ((((long)(b * Tt + t)) * Nn + (n0 + g)) * Mm + m) * Dd + d);
        ushort4 o;
        o.x = f2bf(v.x); o.y = f2bf(v.y); o.z = f2bf(v.z); o.w = f2bf(v.w);
        *(ushort4*)(&lds_x[g][row * QSTR + d]) = o;
    }
    if (tid < 64) {                  // bias column: x~[row][512]=1, 513..527=0
        int g = tid >> 5, row = tid & 31;
        unsigned short* p = &lds_x[g][row * QSTR + 512];
        ushort4 one = {0x3F80, 0, 0, 0}, zz = {0, 0, 0, 0};
        *(ushort4*)(p) = one; *(ushort4*)(p + 4) = zz;
        *(ushort4*)(p + 8) = zz; *(ushort4*)(p + 12) = zz;
    }
    __syncthreads();

    // ---- Phase 2: Y = x~ @ B~  (K = 33 steps of 16) ----
    const unsigned short* abase0 = &lds_x[0][arow * QSTR + (ahalf << 3)];
    const unsigned short* abase1 = &lds_x[1][arow * QSTR + (ahalf << 3)];

    f32x16 aY0, aY1;
    #pragma unroll
    for (int r = 0; r < 16; ++r) { aY0[r] = 0.f; aY1[r] = 0.f; }

    #pragma unroll
    for (int s = 0; s < 33; ++s) {
        int kk = (s < 32) ? KOF(s) : 32;
        bf16x8 bf = pf[s & 3];
        if (s + 4 <= 32) {
            int kn = (s + 4 < 32) ? KOF(s + 4) : 32;
            pf[s & 3] = *(const bf16x8*)(wb + kn * 512);
        }
        bf16x8 a0 = *(const bf16x8*)(abase0 + kk * 16);
        bf16x8 a1 = *(const bf16x8*)(abase1 + kk * 16);
        aY0 = __builtin_amdgcn_mfma_f32_32x32x16_bf16(a0, bf, aY0, 0, 0, 0);
        aY1 = __builtin_amdgcn_mfma_f32_32x32x16_bf16(a1, bf, aY1, 0, 0, 0);
    }

    // ---- Phase 3: fold-reduce scores. Lane holds Y[b=r>>2][m=(r&3)+4h] at
    // e = 32*wave + l5. p[idx], idx = mm*8+k; 5-step fold aligns idx-bit s with
    // lane-bit s -> lane l5 ends with (k=l5&7, mm=l5>>3), m = mm+4*ahalf.
    const int ecol = (wave << 5) + l5;
    #pragma unroll
    for (int g = 0; g < 2; ++g) {
        const f32x16& aY = g ? aY1 : aY0;
        float p[32];
        #pragma unroll
        for (int i = 0; i < 32; ++i) p[i] = 0.f;
        #pragma unroll
        for (int b = 0; b < 4; ++b) {
            float xc[8];
            #pragma unroll
            for (int k = 0; k < 8; ++k)
                xc[k] = bf2f(lds_x[g][(b * 8 + k) * QSTR + ecol]);
            #pragma unroll
            for (int mm = 0; mm < 4; ++mm) {
                float yv = aY[b * 4 + mm];
                #pragma unroll
                for (int k = 0; k < 8; ++k) p[mm * 8 + k] += yv * xc[k];
            }
        }
        const bool b0 = (lane & 1) != 0;
        const bool b1 = (lane & 2) != 0;
        const bool b2 = (lane & 4) != 0;
        const bool b3 = (lane & 8) != 0;
        const bool b4 = (lane & 16) != 0;
        float q16[16];
        #pragma unroll
        for (int i = 0; i < 16; ++i) {
            float keep = b0 ? p[2 * i + 1] : p[2 * i];
            float send = b0 ? p[2 * i] : p[2 * i + 1];
            q16[i] = keep + __shfl_xor(send, 1);
        }
        float q8[8];
        #pragma unroll
        for (int i = 0; i < 8; ++i) {
            float keep = b1 ? q16[2 * i + 1] : q16[2 * i];
            float send = b1 ? q16[2 * i] : q16[2 * i + 1];
            q8[i] = keep + __shfl_xor(send, 2);
        }
        float q4[4];
        #pragma unroll
        for (int i = 0; i < 4; ++i) {
            float keep = b2 ? q8[2 * i + 1] : q8[2 * i];
            float send = b2 ? q8[2 * i] : q8[2 * i + 1];
            q4[i] = keep + __shfl_xor(send, 4);
        }
        float q2[2];
        #pragma unroll
        for (int i = 0; i < 2; ++i) {
            float keep = b3 ? q4[2 * i + 1] : q4[2 * i];
            float send = b3 ? q4[2 * i] : q4[2 * i + 1];
            q2[i] = keep + __shfl_xor(send, 8);
        }
        float sval = (b4 ? q2[1] : q2[0]) + __shfl_xor(b4 ? q2[0] : q2[1], 16);
        int k = l5 & 7, mm = l5 >> 3;
        int m = mm + 4 * ahalf;
        atomicAdd(&lds_s[g][m * 8 + k], sval);
    }

    // early Wv prefetch: lands while softmax + P@x run
    const unsigned short* vb = Wb + VOFF + ((long)wave << 14) + (lane << 3);
    bf16x8 pv[4];
    pv[0] = *(const bf16x8*)(vb + ((0 + rot) & 31) * 512);
    pv[1] = *(const bf16x8*)(vb + ((1 + rot) & 31) * 512);
    pv[2] = *(const bf16x8*)(vb + ((2 + rot) & 31) * 512);
    pv[3] = *(const bf16x8*)(vb + ((3 + rot) & 31) * 512);

    __syncthreads();

    // ---- Phase 4: softmax over k per (g,m) ----
    if (tid < 128) {
        int g = tid >> 6;
        int p = tid & 63;
        float s = lds_s[g][p] * 0.04419417382415922f;   // 1/sqrt(512)
        float mx = s;
        mx = fmaxf(mx, __shfl_xor(mx, 1));
        mx = fmaxf(mx, __shfl_xor(mx, 2));
        mx = fmaxf(mx, __shfl_xor(mx, 4));
        float e = __expf(s - mx);
        float sum = e;
        sum += __shfl_xor(sum, 1);
        sum += __shfl_xor(sum, 2);
        sum += __shfl_xor(sum, 4);
        lds_s[g][p] = e / sum;
    }
    __syncthreads();

    // ---- Phase 5: y = P @ x, in place (column-disjoint per thread) ----
    {
        int d4 = tid & 127;
        int b = (tid >> 7) & 3;
        int g = tid >> 9;
        unsigned short* xr = &lds_x[g][(b << 3) * QSTR + (d4 << 2)];
        float4 xv[8];
        #pragma unroll
        for (int k = 0; k < 8; ++k) {
            ushort4 u = *(const ushort4*)(xr + k * QSTR);
            xv[k].x = bf2f(u.x); xv[k].y = bf2f(u.y);
            xv[k].z = bf2f(u.z); xv[k].w = bf2f(u.w);
        }
        ushort4 yr[8];
        #pragma unroll
        for (int m = 0; m < 8; ++m) {
            float4 o = {0.f, 0.f, 0.f, 0.f};
            #pragma unroll
            for (int k = 0; k < 8; ++k) {
                float w = lds_s[g][(m << 3) + k];
                o.x += w * xv[k].x; o.y += w * xv[k].y;
                o.z += w * xv[k].z; o.w += w * xv[k].w;
            }
            ushort4 oy;
            oy.x = f2bf(o.x); oy.y = f2bf(o.y); oy.z = f2bf(o.z); oy.w = f2bf(o.w);
            yr[m] = oy;
        }
        #pragma unroll
        for (int m = 0; m < 8; ++m) *(ushort4*)(xr + m * QSTR) = yr[m];
    }
    __syncthreads();

    // ---- Phase 6: out = y @ Wv^T + bv, accumulators -> global ----
    {
        f32x16 aV0, aV1;
        #pragma unroll
        for (int r = 0; r < 16; ++r) { aV0[r] = 0.f; aV1[r] = 0.f; }
        #pragma unroll
        for (int s = 0; s < 32; ++s) {
            int kk = (s + rot) & 31;
            bf16x8 wvf = pv[s & 3];
            if (s + 4 < 32) pv[s & 3] = *(const bf16x8*)(vb + (((s + 4 + rot) & 31)) * 512);
            bf16x8 a0 = *(const bf16x8*)(abase0 + kk * 16);
            bf16x8 a1 = *(const bf16x8*)(abase1 + kk * 16);
            aV0 = __builtin_amdgcn_mfma_f32_32x32x16_bf16(a0, wvf, aV0, 0, 0, 0);
            aV1 = __builtin_amdgcn_mfma_f32_32x32x16_bf16(a1, wvf, aV1, 0, 0, 0);
        }
        int f = (wave << 5) + arow;
        float bvv = bv[f];
        float* o0 = out + f;
        #pragma unroll
        for (int r = 0; r < 16; ++r) {
            int mrow = (r & 3) + 8 * (r >> 2) + 4 * ahalf;
            int b = mrow >> 3, m = mrow & 7;
            long base = ((((long)(b * Tt + t)) * Nn + n0) * Mm + m) * Dd;
            o0[base] = aV0[r] + bvv;
            o0[base + (long)Mm * Dd] = aV1[r] + bvv;   // n0+1
        }
    }
    #undef KOF
}

extern "C" void kernel_launch(void* const* d_in, const int* in_sizes, int n_in,
                              void* d_out, int out_size, void* d_ws, size_t ws_size,
                              hipStream_t stream) {
    const float* x  = (const float*)d_in[0];
    const float* Wq = (const float*)d_in[1];
    const float* bq = (const float*)d_in[2];
    const float* Wk = (const float*)d_in[3];
    const float* bv = (const float*)d_in[6];
    const float* Wv = (const float*)d_in[5];
    float* out = (float*)d_out;
    unsigned short* Wb = (unsigned short*)d_ws;   // B~ (540KB) + Wv (512KB) frags

    pack_wv_kernel<<<256, 256, 0, stream>>>(Wv, Wb);
    pack_bqk_kernel<<<256, 256, 0, stream>>>(Wq, Wk, bq, Wb);
    fused_attn_kernel<<<Tt * Nn / 2, 1024, 0, stream>>>(x, Wb, bv, out);
}

// Round 3
// 169.430 us; speedup vs baseline: 1.1905x; 1.1905x over previous
//
#include <hip/hip_runtime.h>

#define Bb 4
#define Tt 64
#define Nn 16
#define Mm 8
#define Dd 512
#define RR 32      // Bb*Mm rows per (t,n) group
#define QSTR 536   // padded LDS row stride in u16: holds 528 (x,1,pad) cols;
                   // 536*2=1072 B = 268 dw == 12 mod 32 -> b128 reads conflict-free
#define VOFF 270336  // u16 offset of Wv region in workspace (16*33*512)

typedef __attribute__((ext_vector_type(8))) short bf16x8;
typedef __attribute__((ext_vector_type(16))) float f32x16;

__device__ __forceinline__ unsigned short f2bf(float f) {
    union { float f; unsigned int u; } v; v.f = f;
    unsigned int r = (v.u + 0x7fffu + ((v.u >> 16) & 1u)) >> 16;  // RNE
    return (unsigned short)r;
}
__device__ __forceinline__ float bf2f(unsigned short h) {
    union { unsigned int u; float f; } v; v.u = ((unsigned int)h) << 16;
    return v.f;
}

// ---- Single pack kernel, grid 512 x 256 threads ----
// Blocks 0..255  : tile (dT = blk>>4, eT = blk&15) of Atilde = Wq^T @ Wk via
//                  MFMA (4 waves split K=512, LDS tree-reduce), written in
//                  B-fragment order; dT==0 blocks also build the ck (kk=32)
//                  bias fragment (ck = Wk^T bq).
// Blocks 256..511: Wv -> bf16 B-fragment order at VOFF (output-driven,
//                  coalesced stores).
__global__ __launch_bounds__(256) void pack_kernel(
    const float* __restrict__ Wq, const float* __restrict__ Wk,
    const float* __restrict__ Wv, const float* __restrict__ bq,
    unsigned short* __restrict__ Wb)
{
    const int tid = threadIdx.x;
    if (blockIdx.x >= 256) {
        int idx = (blockIdx.x - 256) * 256 + tid;   // 65536 ushort4
        int o = idx << 2;
        int j  = o & 7;
        int n  = (o >> 3) & 31;
        int hi = (o >> 8) & 1;
        int ekk = o >> 9;            // e*32+kk
        int kk = ekk & 31;
        int e  = ekk >> 5;           // 0..15
        int row = e * 32 + n;
        int d = kk * 16 + hi * 8 + j;
        float4 v = *(const float4*)(Wv + row * Dd + d);
        ushort4 o4;
        o4.x = f2bf(v.x); o4.y = f2bf(v.y); o4.z = f2bf(v.z); o4.w = f2bf(v.w);
        *(ushort4*)(Wb + VOFF + o) = o4;
        return;
    }

    const int eT = blockIdx.x & 15;
    const int dT = blockIdx.x >> 4;
    const int wave = tid >> 6, lane = tid & 63;
    const int arow = lane & 31, h = lane >> 5;

    // D[d'][e'] = sum_n bf(Wq[n][dT*32+d']) * bf(Wk[n][eT*32+e'])
    // A[row=d'][k=n_loc]: af[j] = Wq[(n0+h*8+j)][dT*32+arow]  (lane-coalesced)
    // B[col=e'][k=n_loc]: bf[j] = Wk[(n0+h*8+j)][eT*32+arow]
    f32x16 acc;
    #pragma unroll
    for (int r = 0; r < 16; ++r) acc[r] = 0.f;

    #pragma unroll
    for (int s = 0; s < 8; ++s) {            // wave w owns K chunk [w*128, w*128+128)
        int n0 = (wave * 8 + s) * 16;
        bf16x8 af, bfr;
        #pragma unroll
        for (int j = 0; j < 8; ++j) {
            int n = n0 + h * 8 + j;
            af[j]  = (short)f2bf(Wq[n * Dd + dT * 32 + arow]);
            bfr[j] = (short)f2bf(Wk[n * Dd + eT * 32 + arow]);
        }
        acc = __builtin_amdgcn_mfma_f32_32x32x16_bf16(af, bfr, acc, 0, 0, 0);
    }

    __shared__ float red[4][1024];
    #pragma unroll
    for (int r = 0; r < 16; ++r) {
        int row = (r & 3) + 8 * (r >> 2) + 4 * h;          // d'
        red[wave][row * 32 + arow] = acc[r];
    }
    __syncthreads();

    #pragma unroll
    for (int i = 0; i < 4; ++i) {
        int el = i * 256 + tid;              // d'*32 + e'
        int dp = el >> 5, ep = el & 31;
        float v = red[0][el] + red[1][el] + red[2][el] + red[3][el];
        int d = dT * 32 + dp;
        int kkg = d >> 4, hh = (d >> 3) & 1, jj = d & 7;
        Wb[(long)(eT * 33 + kkg) * 512 + ((hh * 32 + ep) << 3) + jj] = f2bf(v);
    }

    if (dT == 0) {
        // ck[e'] = sum_n bf(Wk[n][eT*32+e']) * bq[n]; 8 strips of 64 n's
        int ep = tid & 31, strip = tid >> 5;
        float c = 0.f;
        #pragma unroll 8
        for (int n = strip * 64; n < strip * 64 + 64; ++n)
            c += bf2f(f2bf(Wk[n * Dd + eT * 32 + ep])) * bq[n];
        __syncthreads();                     // red reads above all done
        red[0][tid] = c;                     // tid = strip*32 + ep
        long b32 = (long)(eT * 33 + 32) << 9;
        Wb[b32 + tid] = 0; Wb[b32 + 256 + tid] = 0;   // zero bias fragment
        __syncthreads();
        if (tid < 32) {
            float s = 0.f;
            #pragma unroll
            for (int k = 0; k < 8; ++k) s += red[0][k * 32 + tid];
            Wb[b32 + (tid << 3)] = f2bf(s);  // col=tid, h=0, j=0 slot
        }
    }
}

// One block per TWO (t,n) groups. 1024 threads = 16 waves.
// Phase 2: Y = x~ @ [Atilde; ck]  (one GEMM replaces Q and K; biases folded/dropped
//   since softmax is invariant to per-row(m) constants).
// Phase 3: S[m,k] = sum_b sum_e Y[bm,e] x[bk,e] via in-register fold-reduce.
// V eliminated algebraically: out = (P@x)@Wv^T + bv.
__global__ __launch_bounds__(1024, 4) void fused_attn_kernel(
    const float* __restrict__ x, const unsigned short* __restrict__ Wb,
    const float* __restrict__ bv, float* __restrict__ out)
{
    __shared__ unsigned short lds_x[2][RR * QSTR];  // 68,608 B (x~, later y, bf16)
    __shared__ float lds_s[2][64];                  // scores -> probs

    const int tid = threadIdx.x;
    const int lane = tid & 63;
    const int wave = tid >> 6;       // 0..15
    const int arow = lane & 31;
    const int ahalf = lane >> 5;
    const int l5 = lane & 31;

    const int gi0 = blockIdx.x << 1;
    const int t = gi0 >> 4;
    const int n0 = gi0 & 15;
    const int rot = (blockIdx.x * 7) & 31;   // decorrelate L2 address streams

    // B~ fragment base for this wave's e-tile (33 kk-fragments of 512 u16)
    const unsigned short* wb = Wb + (long)wave * (33 * 512) + (lane << 3);
    // kk order: rotate the 32 data steps per block; bias step (32) always last
    #define KOF(s) ((s) + rot >= 32 ? (s) + rot - 32 : (s) + rot)

    // depth-6 ring: ~270cy lookahead covers L2 latency (depth-4 ~180cy did not)
    bf16x8 pf[6];
    #pragma unroll
    for (int i = 0; i < 6; ++i)
        pf[i] = *(const bf16x8*)(wb + KOF(i) * 512);

    if (tid < 128) lds_s[tid >> 6][tid & 63] = 0.f;

    // ---- Phase 1: stage x~ (bf16) ----
    #pragma unroll
    for (int i = 0; i < 8; ++i) {
        int fi = i * 1024 + tid;     // 8192 float4
        int g = fi >> 12;
        int rem = fi & 4095;
        int row = rem >> 7;
        int d = (rem & 127) << 2;
        int b = row >> 3, m = row & 7;
        float4 v = *(const float4*)(x + ((((long)(b * Tt + t)) * Nn + (n0 + g)) * Mm + m) * Dd + d);
        ushort4 o;
        o.x = f2bf(v.x); o.y = f2bf(v.y); o.z = f2bf(v.z); o.w = f2bf(v.w);
        *(ushort4*)(&lds_x[g][row * QSTR + d]) = o;
    }
    if (tid < 64) {                  // bias column: x~[row][512]=1, 513..527=0
        int g = tid >> 5, row = tid & 31;
        unsigned short* p = &lds_x[g][row * QSTR + 512];
        ushort4 one = {0x3F80, 0, 0, 0}, zz = {0, 0, 0, 0};
        *(ushort4*)(p) = one; *(ushort4*)(p + 4) = zz;
        *(ushort4*)(p + 8) = zz; *(ushort4*)(p + 12) = zz;
    }
    __syncthreads();

    // ---- Phase 2: Y = x~ @ B~  (K = 33 steps of 16) ----
    const unsigned short* abase0 = &lds_x[0][arow * QSTR + (ahalf << 3)];
    const unsigned short* abase1 = &lds_x[1][arow * QSTR + (ahalf << 3)];

    f32x16 aY0, aY1;
    #pragma unroll
    for (int r = 0; r < 16; ++r) { aY0[r] = 0.f; aY1[r] = 0.f; }

    #pragma unroll
    for (int s = 0; s < 33; ++s) {
        int kk = (s < 32) ? KOF(s) : 32;
        bf16x8 bf = pf[s % 6];
        if (s + 6 <= 32) {
            int kn = (s + 6 < 32) ? KOF(s + 6) : 32;
            pf[s % 6] = *(const bf16x8*)(wb + kn * 512);
        }
        bf16x8 a0 = *(const bf16x8*)(abase0 + kk * 16);
        bf16x8 a1 = *(const bf16x8*)(abase1 + kk * 16);
        aY0 = __builtin_amdgcn_mfma_f32_32x32x16_bf16(a0, bf, aY0, 0, 0, 0);
        aY1 = __builtin_amdgcn_mfma_f32_32x32x16_bf16(a1, bf, aY1, 0, 0, 0);
    }

    // ---- Phase 3: fold-reduce scores. Lane holds Y[b=r>>2][m=(r&3)+4h] at
    // e = 32*wave + l5. p[idx], idx = mm*8+k; 5-step fold aligns idx-bit s with
    // lane-bit s -> lane l5 ends with (k=l5&7, mm=l5>>3), m = mm+4*ahalf.
    const int ecol = (wave << 5) + l5;
    #pragma unroll
    for (int g = 0; g < 2; ++g) {
        const f32x16& aY = g ? aY1 : aY0;
        float p[32];
        #pragma unroll
        for (int i = 0; i < 32; ++i) p[i] = 0.f;
        #pragma unroll
        for (int b = 0; b < 4; ++b) {
            float xc[8];
            #pragma unroll
            for (int k = 0; k < 8; ++k)
                xc[k] = bf2f(lds_x[g][(b * 8 + k) * QSTR + ecol]);
            #pragma unroll
            for (int mm = 0; mm < 4; ++mm) {
                float yv = aY[b * 4 + mm];
                #pragma unroll
                for (int k = 0; k < 8; ++k) p[mm * 8 + k] += yv * xc[k];
            }
        }
        const bool b0 = (lane & 1) != 0;
        const bool b1 = (lane & 2) != 0;
        const bool b2 = (lane & 4) != 0;
        const bool b3 = (lane & 8) != 0;
        const bool b4 = (lane & 16) != 0;
        float q16[16];
        #pragma unroll
        for (int i = 0; i < 16; ++i) {
            float keep = b0 ? p[2 * i + 1] : p[2 * i];
            float send = b0 ? p[2 * i] : p[2 * i + 1];
            q16[i] = keep + __shfl_xor(send, 1);
        }
        float q8[8];
        #pragma unroll
        for (int i = 0; i < 8; ++i) {
            float keep = b1 ? q16[2 * i + 1] : q16[2 * i];
            float send = b1 ? q16[2 * i] : q16[2 * i + 1];
            q8[i] = keep + __shfl_xor(send, 2);
        }
        float q4[4];
        #pragma unroll
        for (int i = 0; i < 4; ++i) {
            float keep = b2 ? q8[2 * i + 1] : q8[2 * i];
            float send = b2 ? q8[2 * i] : q8[2 * i + 1];
            q4[i] = keep + __shfl_xor(send, 4);
        }
        float q2[2];
        #pragma unroll
        for (int i = 0; i < 2; ++i) {
            float keep = b3 ? q4[2 * i + 1] : q4[2 * i];
            float send = b3 ? q4[2 * i] : q4[2 * i + 1];
            q2[i] = keep + __shfl_xor(send, 8);
        }
        float sval = (b4 ? q2[1] : q2[0]) + __shfl_xor(b4 ? q2[0] : q2[1], 16);
        int k = l5 & 7, mm = l5 >> 3;
        int m = mm + 4 * ahalf;
        atomicAdd(&lds_s[g][m * 8 + k], sval);
    }

    // early Wv prefetch: lands while softmax + P@x run
    const unsigned short* vb = Wb + VOFF + ((long)wave << 14) + (lane << 3);
    bf16x8 pv[4];
    pv[0] = *(const bf16x8*)(vb + ((0 + rot) & 31) * 512);
    pv[1] = *(const bf16x8*)(vb + ((1 + rot) & 31) * 512);
    pv[2] = *(const bf16x8*)(vb + ((2 + rot) & 31) * 512);
    pv[3] = *(const bf16x8*)(vb + ((3 + rot) & 31) * 512);

    __syncthreads();

    // ---- Phase 4: softmax over k per (g,m) ----
    if (tid < 128) {
        int g = tid >> 6;
        int p = tid & 63;
        float s = lds_s[g][p] * 0.04419417382415922f;   // 1/sqrt(512)
        float mx = s;
        mx = fmaxf(mx, __shfl_xor(mx, 1));
        mx = fmaxf(mx, __shfl_xor(mx, 2));
        mx = fmaxf(mx, __shfl_xor(mx, 4));
        float e = __expf(s - mx);
        float sum = e;
        sum += __shfl_xor(sum, 1);
        sum += __shfl_xor(sum, 2);
        sum += __shfl_xor(sum, 4);
        lds_s[g][p] = e / sum;
    }
    __syncthreads();

    // ---- Phase 5: y = P @ x, in place (column-disjoint per thread) ----
    {
        int d4 = tid & 127;
        int b = (tid >> 7) & 3;
        int g = tid >> 9;
        unsigned short* xr = &lds_x[g][(b << 3) * QSTR + (d4 << 2)];
        float4 xv[8];
        #pragma unroll
        for (int k = 0; k < 8; ++k) {
            ushort4 u = *(const ushort4*)(xr + k * QSTR);
            xv[k].x = bf2f(u.x); xv[k].y = bf2f(u.y);
            xv[k].z = bf2f(u.z); xv[k].w = bf2f(u.w);
        }
        ushort4 yr[8];
        #pragma unroll
        for (int m = 0; m < 8; ++m) {
            float4 o = {0.f, 0.f, 0.f, 0.f};
            #pragma unroll
            for (int k = 0; k < 8; ++k) {
                float w = lds_s[g][(m << 3) + k];
                o.x += w * xv[k].x; o.y += w * xv[k].y;
                o.z += w * xv[k].z; o.w += w * xv[k].w;
            }
            ushort4 oy;
            oy.x = f2bf(o.x); oy.y = f2bf(o.y); oy.z = f2bf(o.z); oy.w = f2bf(o.w);
            yr[m] = oy;
        }
        #pragma unroll
        for (int m = 0; m < 8; ++m) *(ushort4*)(xr + m * QSTR) = yr[m];
    }
    __syncthreads();

    // ---- Phase 6: out = y @ Wv^T + bv, accumulators -> global ----
    {
        f32x16 aV0, aV1;
        #pragma unroll
        for (int r = 0; r < 16; ++r) { aV0[r] = 0.f; aV1[r] = 0.f; }
        #pragma unroll
        for (int s = 0; s < 32; ++s) {
            int kk = (s + rot) & 31;
            bf16x8 wvf = pv[s & 3];
            if (s + 4 < 32) pv[s & 3] = *(const bf16x8*)(vb + (((s + 4 + rot) & 31)) * 512);
            bf16x8 a0 = *(const bf16x8*)(abase0 + kk * 16);
            bf16x8 a1 = *(const bf16x8*)(abase1 + kk * 16);
            aV0 = __builtin_amdgcn_mfma_f32_32x32x16_bf16(a0, wvf, aV0, 0, 0, 0);
            aV1 = __builtin_amdgcn_mfma_f32_32x32x16_bf16(a1, wvf, aV1, 0, 0, 0);
        }
        int f = (wave << 5) + arow;
        float bvv = bv[f];
        float* o0 = out + f;
        #pragma unroll
        for (int r = 0; r < 16; ++r) {
            int mrow = (r & 3) + 8 * (r >> 2) + 4 * ahalf;
            int b = mrow >> 3, m = mrow & 7;
            long base = ((((long)(b * Tt + t)) * Nn + n0) * Mm + m) * Dd;
            o0[base] = aV0[r] + bvv;
            o0[base + (long)Mm * Dd] = aV1[r] + bvv;   // n0+1
        }
    }
    #undef KOF
}

extern "C" void kernel_launch(void* const* d_in, const int* in_sizes, int n_in,
                              void* d_out, int out_size, void* d_ws, size_t ws_size,
                              hipStream_t stream) {
    const float* x  = (const float*)d_in[0];
    const float* Wq = (const float*)d_in[1];
    const float* bq = (const float*)d_in[2];
    const float* Wk = (const float*)d_in[3];
    const float* Wv = (const float*)d_in[5];
    const float* bv = (const float*)d_in[6];
    float* out = (float*)d_out;
    unsigned short* Wb = (unsigned short*)d_ws;   // B~ (540KB) + Wv (512KB) frags

    pack_kernel<<<512, 256, 0, stream>>>(Wq, Wk, Wv, bq, Wb);
    fused_attn_kernel<<<Tt * Nn / 2, 1024, 0, stream>>>(x, Wb, bv, out);
}